// Round 2
// baseline (395.180 us; speedup 1.0000x reference)
//
#include <hip/hip_runtime.h>
#include <hip/hip_bf16.h>

// SplitMLP: B=128, C=16, V=32, H=64, O=4, G=10000
// One block (4 waves) per group; wave w owns batch rows [32w, 32w+32).
// NO __syncthreads anywhere: A/W fragments load directly global->reg (fp32->bf16),
// LDS used only for the wave-local H transpose (MFMA C-layout -> B-layout).
// fc2 computed as y^T = W2 @ h^T so outputs store as float4.

typedef __bf16 v8bf __attribute__((ext_vector_type(8)));
typedef float  v4f  __attribute__((ext_vector_type(4)));

#define B_  128
#define C_  16
#define V_  32
#define H_  64
#define O_  4
#define G_  10000
#define HS  104  // Hbuf row stride (bf16): 208 B = 16B-aligned; 16 distinct b128 start banks -> ~2-way (free)

__device__ __forceinline__ v8bf cvt8(float4 lo, float4 hi) {
  v8bf r;
  r[0] = (__bf16)lo.x; r[1] = (__bf16)lo.y; r[2] = (__bf16)lo.z; r[3] = (__bf16)lo.w;
  r[4] = (__bf16)hi.x; r[5] = (__bf16)hi.y; r[6] = (__bf16)hi.z; r[7] = (__bf16)hi.w;
  return r;
}

__device__ __forceinline__ v8bf gload8(const float* __restrict__ p) {
  const float4* p4 = reinterpret_cast<const float4*>(p);
  float4 lo = p4[0];
  float4 hi = p4[1];
  return cvt8(lo, hi);
}

__global__ __launch_bounds__(256, 6)
void splitmlp_kernel(const float* __restrict__ day,
                     const float* __restrict__ items,
                     const float* __restrict__ W1d,
                     const float* __restrict__ W1v,
                     const float* __restrict__ b1,
                     const float* __restrict__ W2,
                     const float* __restrict__ b2,
                     float* __restrict__ out) {
  __shared__ __bf16 Hbuf[B_ * HS];   // 26,624 B -> 6 blocks/CU

  const int t    = threadIdx.x;
  const int g    = blockIdx.x;
  const int w    = t >> 6;
  const int lane = t & 63;
  const int c    = lane & 15;   // col-in-tile (A-row / B-col / D-col)
  const int q    = lane >> 4;   // quad (k-chunk / D-row-block)
  const int r0   = w * 32;      // wave's batch-row base
  const int bA0  = r0 + c;      // A-frag tile0 global batch row
  const int bA1  = bA0 + 16;

  const size_t gV   = (size_t)g * V_;
  const float* W1dg = W1d + (size_t)g * (H_ * C_);
  const float* W1vg = W1v + (size_t)g * (H_ * V_);

  v8bf zf;
#pragma unroll
  for (int i = 0; i < 8; ++i) zf[i] = (__bf16)0.0f;
  v4f zero = {0.f, 0.f, 0.f, 0.f};

  // b1 for this lane's 4 n-tiles (early, overlaps with fragment loads)
  float bias[4];
#pragma unroll
  for (int n = 0; n < 4; ++n) bias[n] = b1[(size_t)g * H_ + n * 16 + c];

  // ---------------- fc1: h(128x64) = [day|items|0] @ W1^T ----------------
  v4f acc[2][4];
#pragma unroll
  for (int m = 0; m < 2; ++m)
#pragma unroll
    for (int n = 0; n < 4; ++n) acc[m][n] = zero;

#pragma unroll
  for (int kt = 0; kt < 2; ++kt) {
    const int  k0    = kt * 32 + q * 8;     // lane's 8-wide k-chunk
    const bool isday = (k0 < 16);
    const bool valid = (k0 < 48);

    // A fragments: lane holds A[b][k0..k0+8)
    const float* pa0 = isday ? (day + bA0 * C_ + k0)
                     : valid ? (items + (size_t)bA0 * (G_ * V_) + gV + (k0 - 16))
                             : day;                       // clamped; zeroed below
    const float* pa1 = isday ? (day + bA1 * C_ + k0)
                     : valid ? (items + (size_t)bA1 * (G_ * V_) + gV + (k0 - 16))
                             : day;
    v8bf a0 = gload8(pa0);
    v8bf a1 = gload8(pa1);
    if (!valid) { a0 = zf; a1 = zf; }   // k >= 48 contributes 0 (B garbage OK)

#pragma unroll
    for (int n = 0; n < 4; ++n) {
      const int h = n * 16 + c;
      // B fragment: lane holds W1[h][k0..k0+8)  (B[k][n] layout)
      const float* pw = isday ? (W1dg + h * C_ + k0)
                      : valid ? (W1vg + h * V_ + (k0 - 16))
                              : day;                      // clamped; A side is zero
      v8bf bw = gload8(pw);
      acc[0][n] = __builtin_amdgcn_mfma_f32_16x16x32_bf16(a0, bw, acc[0][n], 0, 0, 0);
      acc[1][n] = __builtin_amdgcn_mfma_f32_16x16x32_bf16(a1, bw, acc[1][n], 0, 0, 0);
    }
  }

  // epilogue: +b1, ReLU -> Hbuf (wave-local rows; in-wave LDS ordering, no barrier)
  // C/D layout: col = n*16+c, row = r0 + m*16 + q*4 + r
#pragma unroll
  for (int n = 0; n < 4; ++n)
#pragma unroll
    for (int m = 0; m < 2; ++m)
#pragma unroll
      for (int r = 0; r < 4; ++r) {
        float v = fmaxf(acc[m][n][r] + bias[n], 0.0f);
        Hbuf[(r0 + m * 16 + q * 4 + r) * HS + n * 16 + c] = (__bf16)v;
      }

  // ---------------- fc2: y^T(4x128) = W2(4x64,pad16) @ h^T ----------------
  v4f y0 = zero, y1 = zero;
#pragma unroll
  for (int kt = 0; kt < 2; ++kt) {
    const int k0 = kt * 32 + q * 8;
    // A fragment = W2: lane holds W2[o=c][k0..k0+8), rows 4..15 zero
    const float* pw2 = (c < O_) ? (W2 + (size_t)g * (O_ * H_) + c * H_ + k0) : day;
    v8bf wf = gload8(pw2);
    if (c >= O_) wf = zf;
    // B fragment = h^T: lane holds h[batch = r0(+16) + c][k0..k0+8)
    v8bf h0 = *reinterpret_cast<const v8bf*>(&Hbuf[(r0 + c) * HS + k0]);
    v8bf h1 = *reinterpret_cast<const v8bf*>(&Hbuf[(r0 + 16 + c) * HS + k0]);
    y0 = __builtin_amdgcn_mfma_f32_16x16x32_bf16(wf, h0, y0, 0, 0, 0);
    y1 = __builtin_amdgcn_mfma_f32_16x16x32_bf16(wf, h1, y1, 0, 0, 0);
  }

  // store: D[row=o][col=batch] -> q==0 lanes hold o=0..3 in regs -> float4 per batch
  if (q == 0) {
    const float4 b2v = *reinterpret_cast<const float4*>(b2 + (size_t)g * O_);
    float4 o0, o1;
    o0.x = y0[0] + b2v.x; o0.y = y0[1] + b2v.y; o0.z = y0[2] + b2v.z; o0.w = y0[3] + b2v.w;
    o1.x = y1[0] + b2v.x; o1.y = y1[1] + b2v.y; o1.z = y1[2] + b2v.z; o1.w = y1[3] + b2v.w;
    *reinterpret_cast<float4*>(out + (size_t)(r0 + c) * (G_ * O_) + (size_t)g * O_) = o0;
    *reinterpret_cast<float4*>(out + (size_t)(r0 + 16 + c) * (G_ * O_) + (size_t)g * O_) = o1;
  }
}

extern "C" void kernel_launch(void* const* d_in, const int* in_sizes, int n_in,
                              void* d_out, int out_size, void* d_ws, size_t ws_size,
                              hipStream_t stream) {
  const float* day   = (const float*)d_in[0];
  const float* items = (const float*)d_in[1];
  const float* W1d   = (const float*)d_in[2];
  const float* W1v   = (const float*)d_in[3];
  const float* b1    = (const float*)d_in[4];
  const float* W2    = (const float*)d_in[5];
  const float* b2    = (const float*)d_in[6];
  float* out = (float*)d_out;
  splitmlp_kernel<<<G_, 256, 0, stream>>>(day, items, W1d, W1v, b1, W2, b2, out);
}